// Round 1
// baseline (223.199 us; speedup 1.0000x reference)
//
#include <hip/hip_runtime.h>

#define BB 4
#define LL 4096
#define DD 128

typedef __attribute__((ext_vector_type(8))) short short8;
typedef __attribute__((ext_vector_type(4))) float f32x4;

__device__ __forceinline__ unsigned short f2bf(float x) {
  union { float f; unsigned int u; } c; c.f = x;
  unsigned int r = (c.u + 0x7FFFu + ((c.u >> 16) & 1u)) >> 16;
  return (unsigned short)r;
}

// ---- prepass 1: fp32 -> bf16, same layout (for K) ----
__global__ __launch_bounds__(256) void cvt_bf16_k(const float* __restrict__ X,
                                                  unsigned short* __restrict__ Y) {
  size_t i = ((size_t)blockIdx.x * 256 + threadIdx.x) * 8;
  const float4* p = (const float4*)(X + i);
  float4 a = p[0], b = p[1];
  union { unsigned short h[8]; uint4 v; } o;
  o.h[0] = f2bf(a.x); o.h[1] = f2bf(a.y); o.h[2] = f2bf(a.z); o.h[3] = f2bf(a.w);
  o.h[4] = f2bf(b.x); o.h[5] = f2bf(b.y); o.h[6] = f2bf(b.z); o.h[7] = f2bf(b.w);
  *(uint4*)(Y + i) = o.v;
}

// ---- prepass 2: V [B][L][D] fp32 -> Vt [B][D][L] bf16 (LDS tile transpose) ----
__global__ __launch_bounds__(256) void cvt_v_t(const float* __restrict__ V,
                                               unsigned short* __restrict__ Vt) {
  __shared__ unsigned short tile[64 * 132];   // [key][dim], pad 4
  int b  = blockIdx.x >> 6;
  int kt = (blockIdx.x & 63) << 6;
  int t = threadIdx.x;
  int keyi = t >> 5, dim = (t & 31) * 4;
#pragma unroll
  for (int j = 0; j < 8; ++j) {
    int key = keyi + j * 8;
    float4 x = *(const float4*)(V + ((size_t)b * LL + kt + key) * DD + dim);
    unsigned int w0 = f2bf(x.x) | ((unsigned int)f2bf(x.y) << 16);
    unsigned int w1 = f2bf(x.z) | ((unsigned int)f2bf(x.w) << 16);
    uint2 pk; pk.x = w0; pk.y = w1;
    *(uint2*)(tile + key * 132 + dim) = pk;
  }
  __syncthreads();
  int k4 = (t & 15) * 4, d0 = t >> 4;
#pragma unroll
  for (int j = 0; j < 8; ++j) {
    int d = d0 + j * 16;
    unsigned int lo = tile[(k4 + 0) * 132 + d] | ((unsigned int)tile[(k4 + 1) * 132 + d] << 16);
    unsigned int hi = tile[(k4 + 2) * 132 + d] | ((unsigned int)tile[(k4 + 3) * 132 + d] << 16);
    uint2 pk; pk.x = lo; pk.y = hi;
    *(uint2*)(Vt + ((size_t)b * DD + d) * LL + kt + k4) = pk;
  }
}

// ---- main: flash-style causal attention ----
// grid 256: 4 waves/block, each wave 16 q-rows (64-row Q tile per block).
// Kb: bf16 [B][L][D]; Vt: bf16 [B][D][L].
__global__ __launch_bounds__(256) void attn_fwd(const float* __restrict__ Q,
                                                const unsigned short* __restrict__ Kb,
                                                const unsigned short* __restrict__ Vt,
                                                float* __restrict__ Out) {
  __shared__ unsigned short Ks[64 * 136];     // [key][dim], pad 8 (16B-aligned rows)
  __shared__ unsigned short Vs[128 * 72];     // [dim][key], pad 8
  __shared__ unsigned short Ps[4][16 * 72];   // per-wave P, [qrow][key], pad 8

  int bid = blockIdx.x;
  int b = bid & 3;
  int t = 63 - (bid >> 2);                    // biggest q-tiles dispatched first
  int q0 = t << 6;
  int tid = threadIdx.x;
  int wave = tid >> 6;
  int lane = tid & 63;
  int l = lane & 15, g = lane >> 4;

  // Q fragments (A-layout: row = lane&15, k = (lane>>4)*8+j), scale*log2e folded in
  const float SC = 0.08838834764831845f * 1.4426950408889634f;
  short8 qf[4];
  {
    const float* qp = Q + ((size_t)b * LL + q0 + wave * 16 + l) * DD + g * 8;
#pragma unroll
    for (int c = 0; c < 4; ++c) {
      float4 x = *(const float4*)(qp + c * 32);
      float4 y = *(const float4*)(qp + c * 32 + 4);
      short8 f;
      f[0] = (short)f2bf(x.x * SC); f[1] = (short)f2bf(x.y * SC);
      f[2] = (short)f2bf(x.z * SC); f[3] = (short)f2bf(x.w * SC);
      f[4] = (short)f2bf(y.x * SC); f[5] = (short)f2bf(y.y * SC);
      f[6] = (short)f2bf(y.z * SC); f[7] = (short)f2bf(y.w * SC);
      qf[c] = f;
    }
  }

  f32x4 acc[8];
#pragma unroll
  for (int i = 0; i < 8; ++i) acc[i] = (f32x4){0.f, 0.f, 0.f, 0.f};
  float m0[4] = {-1e30f, -1e30f, -1e30f, -1e30f};
  float ls[4] = {0.f, 0.f, 0.f, 0.f};

  int kend = q0 + 63;                  // block-max valid key
  int wkend = q0 + wave * 16 + 15;     // wave-max valid key
  int skey = tid >> 2, spart = tid & 3;    // K staging: 16KB, fully coalesced
  int sdim = tid >> 1, shalf = tid & 1;    // V staging
  unsigned short* Pw = Ps[wave];

  for (int kt = 0; kt <= kend; kt += 64) {
    __syncthreads();   // protect LDS from previous iteration's readers
    {
      const uint4* src = (const uint4*)(Kb + ((size_t)b * LL + kt + skey) * DD + spart * 32);
      uint4* dst = (uint4*)(Ks + skey * 136 + spart * 32);
#pragma unroll
      for (int i = 0; i < 4; ++i) dst[i] = src[i];
      const uint4* vsrc = (const uint4*)(Vt + ((size_t)b * DD + sdim) * LL + kt + shalf * 32);
      uint4* vdst = (uint4*)(Vs + sdim * 72 + shalf * 32);
#pragma unroll
      for (int i = 0; i < 4; ++i) vdst[i] = vsrc[i];
    }
    __syncthreads();
    if (kt > wkend) continue;   // this wave's rows all precede the tile; barriers stay matched

    // S = Q K^T  (C-layout: row=(g*4+r) q-row offset, col=l key offset)
    f32x4 s[4];
#pragma unroll
    for (int nt = 0; nt < 4; ++nt) {
      const unsigned short* kp = Ks + (nt * 16 + l) * 136 + g * 8;
      f32x4 a = (f32x4){0.f, 0.f, 0.f, 0.f};
#pragma unroll
      for (int c = 0; c < 4; ++c) {
        short8 kf = *(const short8*)(kp + c * 32);
        a = __builtin_amdgcn_mfma_f32_16x16x32_bf16(qf[c], kf, a, 0, 0, 0);
      }
      s[nt] = a;
    }

    // causal mask (only the final tile of each wave triggers this)
    int qr = q0 + wave * 16 + g * 4;
    if (kt + 63 > q0 + wave * 16) {
#pragma unroll
      for (int nt = 0; nt < 4; ++nt) {
        int key = kt + nt * 16 + l;
#pragma unroll
        for (int r = 0; r < 4; ++r)
          if (key > qr + r) s[nt][r] = -1e30f;
      }
    }

    // online softmax (stats per row; rows live in regs r, reduce across l-lanes)
    float mt[4], al[4], rs[4];
#pragma unroll
    for (int r = 0; r < 4; ++r)
      mt[r] = fmaxf(fmaxf(s[0][r], s[1][r]), fmaxf(s[2][r], s[3][r]));
#pragma unroll
    for (int off = 1; off < 16; off <<= 1) {
#pragma unroll
      for (int r = 0; r < 4; ++r)
        mt[r] = fmaxf(mt[r], __shfl_xor(mt[r], off));
    }
#pragma unroll
    for (int r = 0; r < 4; ++r) {
      float mn = fmaxf(m0[r], mt[r]);
      al[r] = exp2f(m0[r] - mn);
      m0[r] = mn;
    }
#pragma unroll
    for (int nt = 0; nt < 4; ++nt) {
#pragma unroll
      for (int r = 0; r < 4; ++r)
        s[nt][r] = exp2f(s[nt][r] - m0[r]);
    }
#pragma unroll
    for (int r = 0; r < 4; ++r)
      rs[r] = (s[0][r] + s[1][r]) + (s[2][r] + s[3][r]);
#pragma unroll
    for (int off = 1; off < 16; off <<= 1) {
#pragma unroll
      for (int r = 0; r < 4; ++r)
        rs[r] += __shfl_xor(rs[r], off);
    }
    f32x4 alv = {al[0], al[1], al[2], al[3]};
#pragma unroll
    for (int r = 0; r < 4; ++r)
      ls[r] = ls[r] * al[r] + rs[r];
#pragma unroll
    for (int dt = 0; dt < 8; ++dt) acc[dt] *= alv;

    // P: C-layout -> LDS -> A-layout (wave-private buffer, lgkmcnt-ordered)
#pragma unroll
    for (int nt = 0; nt < 4; ++nt) {
#pragma unroll
      for (int r = 0; r < 4; ++r)
        Pw[(g * 4 + r) * 72 + nt * 16 + l] = f2bf(s[nt][r]);
    }

    // O += P V   (B-frag: 8 consecutive keys per lane from Vt row = dim)
#pragma unroll
    for (int kc = 0; kc < 2; ++kc) {
      short8 pa = *(const short8*)(Pw + l * 72 + kc * 32 + g * 8);
#pragma unroll
      for (int dt = 0; dt < 8; ++dt) {
        short8 vb = *(const short8*)(Vs + (dt * 16 + l) * 72 + kc * 32 + g * 8);
        acc[dt] = __builtin_amdgcn_mfma_f32_16x16x32_bf16(pa, vb, acc[dt], 0, 0, 0);
      }
    }
  }

  // epilogue: O /= l, store fp32
  float inv[4];
#pragma unroll
  for (int r = 0; r < 4; ++r) inv[r] = 1.0f / ls[r];
  float* op = Out + ((size_t)b * LL + q0 + wave * 16) * DD;
#pragma unroll
  for (int dt = 0; dt < 8; ++dt) {
#pragma unroll
    for (int r = 0; r < 4; ++r)
      op[(g * 4 + r) * DD + dt * 16 + l] = acc[dt][r] * inv[r];
  }
}

extern "C" void kernel_launch(void* const* d_in, const int* in_sizes, int n_in,
                              void* d_out, int out_size, void* d_ws, size_t ws_size,
                              hipStream_t stream) {
  const float* K = (const float*)d_in[0];   // "key"
  const float* Q = (const float*)d_in[1];   // "query"
  const float* V = (const float*)d_in[2];   // "value"
  float* Out = (float*)d_out;

  unsigned short* Kb = (unsigned short*)d_ws;            // 4 MB
  unsigned short* Vt = Kb + (size_t)BB * LL * DD;        // 4 MB

  cvt_bf16_k<<<dim3((BB * LL * DD) / (256 * 8)), dim3(256), 0, stream>>>(K, Kb);
  cvt_v_t<<<dim3(BB * (LL / 64)), dim3(256), 0, stream>>>(V, Vt);
  attn_fwd<<<dim3(BB * (LL / 64)), dim3(256), 0, stream>>>(Q, Kb, Vt, Out);
}

// Round 2
// 216.309 us; speedup vs baseline: 1.0319x; 1.0319x over previous
//
#include <hip/hip_runtime.h>

#define BB 4
#define LL 4096
#define DD 128

typedef __attribute__((ext_vector_type(8))) short short8;
typedef __attribute__((ext_vector_type(4))) float f32x4;

__device__ __forceinline__ unsigned short f2bf(float x) {
  union { float f; unsigned int u; } c; c.f = x;
  unsigned int r = (c.u + 0x7FFFu + ((c.u >> 16) & 1u)) >> 16;
  return (unsigned short)r;
}

// ---- fused prepass: K fp32->bf16 (same layout) + V fp32->bf16 transposed [B][D][L] ----
__global__ __launch_bounds__(256) void prep(const float* __restrict__ K,
                                            const float* __restrict__ V,
                                            unsigned short* __restrict__ Kb,
                                            unsigned short* __restrict__ Vt) {
  __shared__ unsigned short tile[64 * 132];   // [key][dim], pad 4
  int b  = blockIdx.x >> 6;
  int kt = (blockIdx.x & 63) << 6;
  int t = threadIdx.x;

  // K: thread handles key=t>>2, dims (t&3)*32..+31  (32 floats -> 32 bf16)
  {
    int key = t >> 2, part = t & 3;
    const float* src = K + ((size_t)b * LL + kt + key) * DD + part * 32;
    unsigned short* dst = Kb + ((size_t)b * LL + kt + key) * DD + part * 32;
#pragma unroll
    for (int j = 0; j < 4; ++j) {
      float4 x = *(const float4*)(src + j * 8);
      float4 y = *(const float4*)(src + j * 8 + 4);
      union { unsigned short h[8]; uint4 v; } o;
      o.h[0] = f2bf(x.x); o.h[1] = f2bf(x.y); o.h[2] = f2bf(x.z); o.h[3] = f2bf(x.w);
      o.h[4] = f2bf(y.x); o.h[5] = f2bf(y.y); o.h[6] = f2bf(y.z); o.h[7] = f2bf(y.w);
      *(uint4*)(dst + j * 8) = o.v;
    }
  }

  // V transpose via LDS
  int keyi = t >> 5, dim = (t & 31) * 4;
#pragma unroll
  for (int j = 0; j < 8; ++j) {
    int key = keyi + j * 8;
    float4 x = *(const float4*)(V + ((size_t)b * LL + kt + key) * DD + dim);
    unsigned int w0 = f2bf(x.x) | ((unsigned int)f2bf(x.y) << 16);
    unsigned int w1 = f2bf(x.z) | ((unsigned int)f2bf(x.w) << 16);
    uint2 pk; pk.x = w0; pk.y = w1;
    *(uint2*)(tile + key * 132 + dim) = pk;
  }
  __syncthreads();
  int k4 = (t & 15) * 4, d0 = t >> 4;
#pragma unroll
  for (int j = 0; j < 8; ++j) {
    int d = d0 + j * 16;
    unsigned int lo = tile[(k4 + 0) * 132 + d] | ((unsigned int)tile[(k4 + 1) * 132 + d] << 16);
    unsigned int hi = tile[(k4 + 2) * 132 + d] | ((unsigned int)tile[(k4 + 3) * 132 + d] << 16);
    uint2 pk; pk.x = lo; pk.y = hi;
    *(uint2*)(Vt + ((size_t)b * DD + d) * LL + kt + k4) = pk;
  }
}

// ---- main: flash-style causal attention, sequence-split across blocks ----
// C = key-tiles (of 64 keys) per chunk. Tile t (64 q-rows) has nch = t/C+1 chunks.
// Per batch: group g (tiles [gC,(g+1)C)) has C*(g+1) blocks; perBatch = sum.
// Single-chunk tiles write Out directly; multi-chunk write partials (acc,m,l) to ws.
__global__ __launch_bounds__(256) void attn_fwd(const float* __restrict__ Q,
                                                const unsigned short* __restrict__ Kb,
                                                const unsigned short* __restrict__ Vt,
                                                float* __restrict__ Out,
                                                float* __restrict__ partO,
                                                float2* __restrict__ stats,
                                                int C, int perBatch) {
  __shared__ unsigned short Ks[64 * 136];     // [key][dim], pad 8
  __shared__ unsigned short Vs[128 * 72];     // [dim][key], pad 8
  __shared__ unsigned short Ps[4][16 * 72];   // per-wave P

  // block -> (b, t, chunk c); reversed so heaviest (largest t) dispatch first
  int idx = (int)gridDim.x - 1 - (int)blockIdx.x;
  int b = idx / perBatch;
  int rr = idx % perBatch;
  int slot = idx;                 // partial slot id (b*perBatch + r)
  int g = 0;
  while (true) { int cnt = C * (g + 1); if (rr < cnt) break; rr -= cnt; ++g; }
  int t = g * C + rr / (g + 1);
  int c = rr % (g + 1);
  int nch = t / C + 1;
  int nIters = min(C, t + 1 - c * C);
  int q0 = t << 6;
  int ktBase = (c * C) << 6;

  int tid = threadIdx.x;
  int wave = tid >> 6;
  int lane = tid & 63;
  int l = lane & 15, gq = lane >> 4;

  // Q fragments (A-layout), scale*log2e folded in
  const float SC = 0.08838834764831845f * 1.4426950408889634f;
  short8 qf[4];
  {
    const float* qp = Q + ((size_t)b * LL + q0 + wave * 16 + l) * DD + gq * 8;
#pragma unroll
    for (int cc = 0; cc < 4; ++cc) {
      float4 x = *(const float4*)(qp + cc * 32);
      float4 y = *(const float4*)(qp + cc * 32 + 4);
      short8 f;
      f[0] = (short)f2bf(x.x * SC); f[1] = (short)f2bf(x.y * SC);
      f[2] = (short)f2bf(x.z * SC); f[3] = (short)f2bf(x.w * SC);
      f[4] = (short)f2bf(y.x * SC); f[5] = (short)f2bf(y.y * SC);
      f[6] = (short)f2bf(y.z * SC); f[7] = (short)f2bf(y.w * SC);
      qf[cc] = f;
    }
  }

  f32x4 acc[8];
#pragma unroll
  for (int i = 0; i < 8; ++i) acc[i] = (f32x4){0.f, 0.f, 0.f, 0.f};
  float m0[4] = {-1e30f, -1e30f, -1e30f, -1e30f};
  float ls[4] = {0.f, 0.f, 0.f, 0.f};

  int wkend = q0 + wave * 16 + 15;          // wave-max valid key
  int skey = tid >> 2, spart = tid & 3;     // K staging addressing
  int sdim = tid >> 1, shalf = tid & 1;     // V staging addressing
  unsigned short* Pw = Ps[wave];

  const uint4* ksrc0 = (const uint4*)(Kb + ((size_t)b * LL + skey) * DD + spart * 32);
  const uint4* vsrc0 = (const uint4*)(Vt + ((size_t)b * DD + sdim) * LL + shalf * 32);
  uint4* kdst = (uint4*)(Ks + skey * 136 + spart * 32);
  uint4* vdst = (uint4*)(Vs + sdim * 72 + shalf * 32);

  uint4 kreg[4], vreg[4];
  // prefetch tile 0
  {
    const uint4* s1 = ksrc0 + (size_t)ktBase * DD / 8;
    const uint4* s2 = vsrc0 + (size_t)ktBase / 8;
#pragma unroll
    for (int i = 0; i < 4; ++i) { kreg[i] = s1[i]; vreg[i] = s2[i]; }
  }

  for (int it = 0; it < nIters; ++it) {
    int kt = ktBase + it * 64;
    __syncthreads();   // prior readers done before overwrite
#pragma unroll
    for (int i = 0; i < 4; ++i) { kdst[i] = kreg[i]; vdst[i] = vreg[i]; }
    __syncthreads();
    if (it + 1 < nIters) {       // issue next tile's loads; consumed next iteration
      const uint4* s1 = ksrc0 + (size_t)(kt + 64) * DD / 8;
      const uint4* s2 = vsrc0 + (size_t)(kt + 64) / 8;
#pragma unroll
      for (int i = 0; i < 4; ++i) { kreg[i] = s1[i]; vreg[i] = s2[i]; }
    }

    if (kt > wkend) continue;    // wave's rows precede this tile (barriers already done)

    // S = Q K^T
    f32x4 s[4];
#pragma unroll
    for (int nt = 0; nt < 4; ++nt) {
      const unsigned short* kp = Ks + (nt * 16 + l) * 136 + gq * 8;
      f32x4 a = (f32x4){0.f, 0.f, 0.f, 0.f};
#pragma unroll
      for (int cc = 0; cc < 4; ++cc) {
        short8 kf = *(const short8*)(kp + cc * 32);
        a = __builtin_amdgcn_mfma_f32_16x16x32_bf16(qf[cc], kf, a, 0, 0, 0);
      }
      s[nt] = a;
    }

    // causal mask (diagonal tiles only)
    int qr = q0 + wave * 16 + gq * 4;
    if (kt + 63 > q0 + wave * 16) {
#pragma unroll
      for (int nt = 0; nt < 4; ++nt) {
        int key = kt + nt * 16 + l;
#pragma unroll
        for (int r = 0; r < 4; ++r)
          if (key > qr + r) s[nt][r] = -1e30f;
      }
    }

    // online softmax
    float mt[4], al[4], rs[4];
#pragma unroll
    for (int r = 0; r < 4; ++r)
      mt[r] = fmaxf(fmaxf(s[0][r], s[1][r]), fmaxf(s[2][r], s[3][r]));
#pragma unroll
    for (int off = 1; off < 16; off <<= 1)
#pragma unroll
      for (int r = 0; r < 4; ++r)
        mt[r] = fmaxf(mt[r], __shfl_xor(mt[r], off));
#pragma unroll
    for (int r = 0; r < 4; ++r) {
      float mn = fmaxf(m0[r], mt[r]);
      al[r] = exp2f(m0[r] - mn);
      m0[r] = mn;
    }
#pragma unroll
    for (int nt = 0; nt < 4; ++nt)
#pragma unroll
      for (int r = 0; r < 4; ++r)
        s[nt][r] = exp2f(s[nt][r] - m0[r]);
#pragma unroll
    for (int r = 0; r < 4; ++r)
      rs[r] = (s[0][r] + s[1][r]) + (s[2][r] + s[3][r]);
#pragma unroll
    for (int off = 1; off < 16; off <<= 1)
#pragma unroll
      for (int r = 0; r < 4; ++r)
        rs[r] += __shfl_xor(rs[r], off);
    f32x4 alv = {al[0], al[1], al[2], al[3]};
#pragma unroll
    for (int r = 0; r < 4; ++r)
      ls[r] = ls[r] * al[r] + rs[r];
#pragma unroll
    for (int dt = 0; dt < 8; ++dt) acc[dt] *= alv;

    // P: C-layout -> LDS -> A-layout
#pragma unroll
    for (int nt = 0; nt < 4; ++nt)
#pragma unroll
      for (int r = 0; r < 4; ++r)
        Pw[(gq * 4 + r) * 72 + nt * 16 + l] = f2bf(s[nt][r]);

    // O += P V
#pragma unroll
    for (int kc = 0; kc < 2; ++kc) {
      short8 pa = *(const short8*)(Pw + l * 72 + kc * 32 + gq * 8);
#pragma unroll
      for (int dt = 0; dt < 8; ++dt) {
        short8 vb = *(const short8*)(Vs + (dt * 16 + l) * 72 + kc * 32 + gq * 8);
        acc[dt] = __builtin_amdgcn_mfma_f32_16x16x32_bf16(pa, vb, acc[dt], 0, 0, 0);
      }
    }
  }

  if (nch == 1) {
    float inv[4];
#pragma unroll
    for (int r = 0; r < 4; ++r) inv[r] = 1.0f / ls[r];
    float* op = Out + ((size_t)b * LL + q0 + wave * 16) * DD;
#pragma unroll
    for (int dt = 0; dt < 8; ++dt)
#pragma unroll
      for (int r = 0; r < 4; ++r)
        op[(gq * 4 + r) * DD + dt * 16 + l] = acc[dt][r] * inv[r];
  } else {
    float* op = partO + (size_t)slot * 64 * 128 + (size_t)(wave * 16) * 128;
#pragma unroll
    for (int dt = 0; dt < 8; ++dt)
#pragma unroll
      for (int r = 0; r < 4; ++r)
        op[(gq * 4 + r) * 128 + dt * 16 + l] = acc[dt][r];
    if (l == 0) {
#pragma unroll
      for (int r = 0; r < 4; ++r) {
        float2 st; st.x = m0[r]; st.y = ls[r];
        stats[(size_t)slot * 64 + wave * 16 + gq * 4 + r] = st;
      }
    }
  }
}

// ---- merge partials for multi-chunk tiles (t >= C) ----
__global__ __launch_bounds__(256) void merge(const float* __restrict__ partO,
                                             const float2* __restrict__ stats,
                                             float* __restrict__ Out,
                                             int C, int perBatch) {
  int multi = 64 - C;
  int b = blockIdx.x / multi;
  int t = C + blockIdx.x % multi;
  int g = t / C;
  int nch = g + 1;
  int base = C * g * (g + 1) / 2;
  int slot0 = b * perBatch + base + (t - g * C) * nch;

  int tid = threadIdx.x;
  int row = tid >> 2;
  int dpart = (tid & 3) * 32;

  float m = -1e30f;
  for (int cc = 0; cc < nch; ++cc)
    m = fmaxf(m, stats[(size_t)(slot0 + cc) * 64 + row].x);
  float lsum = 0.f, w[4];
  for (int cc = 0; cc < nch; ++cc) {
    float2 st = stats[(size_t)(slot0 + cc) * 64 + row];
    w[cc] = exp2f(st.x - m);
    lsum += w[cc] * st.y;
  }
  float inv = 1.0f / lsum;

  float4 o[8];
#pragma unroll
  for (int j = 0; j < 8; ++j) o[j] = (float4){0.f, 0.f, 0.f, 0.f};
  for (int cc = 0; cc < nch; ++cc) {
    const float4* p = (const float4*)(partO + (size_t)(slot0 + cc) * 64 * 128 + (size_t)row * 128 + dpart);
    float wc = w[cc];
#pragma unroll
    for (int j = 0; j < 8; ++j) {
      float4 x = p[j];
      o[j].x += wc * x.x; o[j].y += wc * x.y; o[j].z += wc * x.z; o[j].w += wc * x.w;
    }
  }
  float4* op = (float4*)(Out + ((size_t)b * LL + (t << 6) + row) * DD + dpart);
#pragma unroll
  for (int j = 0; j < 8; ++j) {
    o[j].x *= inv; o[j].y *= inv; o[j].z *= inv; o[j].w *= inv;
    op[j] = o[j];
  }
}

extern "C" void kernel_launch(void* const* d_in, const int* in_sizes, int n_in,
                              void* d_out, int out_size, void* d_ws, size_t ws_size,
                              hipStream_t stream) {
  const float* K = (const float*)d_in[0];   // "key"
  const float* Q = (const float*)d_in[1];   // "query"
  const float* V = (const float*)d_in[2];   // "value"
  float* Out = (float*)d_out;

  const size_t convBytes = (size_t)2 * BB * LL * DD * 2;   // Kb + Vt, 8 MB
  unsigned short* Kb = (unsigned short*)d_ws;
  unsigned short* Vt = Kb + (size_t)BB * LL * DD;

  // split config: C=16 (1024-key chunks) if workspace fits partials, else no split
  int C = 16, perBatch = 160;
  {
    size_t slots = (size_t)BB * perBatch;
    size_t need = convBytes + slots * 64 * 128 * 4 + slots * 64 * 8;
    if (ws_size < need) { C = 64; perBatch = 64; }
  }
  size_t slots = (size_t)BB * perBatch;
  float* partO = (float*)((char*)d_ws + convBytes);
  float2* stats = (float2*)((char*)d_ws + convBytes + slots * 64 * 128 * 4);

  prep<<<dim3(BB * (LL / 64)), dim3(256), 0, stream>>>(K, V, Kb, Vt);
  attn_fwd<<<dim3(BB * perBatch), dim3(256), 0, stream>>>(Q, Kb, Vt, Out, partO, stats, C, perBatch);
  if (C < 64)
    merge<<<dim3(BB * (64 - C)), dim3(256), 0, stream>>>(partO, stats, Out, C, perBatch);
}